// Round 10
// baseline (324.337 us; speedup 1.0000x reference)
//
#include <hip/hip_runtime.h>
#include <math.h>

#define N_ROWS 32768
#define DIM 256
#define K_CODES 1024
#define MARGIN 2e-3f

typedef float f32x4v __attribute__((ext_vector_type(4)));
typedef short s16x8 __attribute__((ext_vector_type(8)));

// ---- ws layout (bytes) ----
// flaglist int[32768]     @ 0          (MFMA path; fallback uses as x2 floats)
// w2       float[1024]    @ 131072
// whi      ushort[262144] @ 135168
// wlo      ushort[262144] @ 659456
// flagcnt  int            @ 1183744
#define WS_NEEDED ((size_t)1183748)

__device__ __forceinline__ unsigned short bf16_rne(float f) {
    unsigned int u = __float_as_uint(f);
    unsigned int r = (u + 0x7FFFu + ((u >> 16) & 1u)) >> 16;
    return (unsigned short)r;
}
__device__ __forceinline__ float bf16_f32(unsigned short h) {
    return __uint_as_float(((unsigned int)h) << 16);
}

// ---------------------------------------------------------------------------
// numpy-replica pairwise sum of squares (AVX512 path) — bitwise == np.sum(x*x)
// ---------------------------------------------------------------------------
__device__ __forceinline__ float np_block128_sumsq(const float* e) {
#pragma clang fp contract(off)
    float s[16];
#pragma unroll
    for (int l = 0; l < 16; ++l) {
        float a0 = e[l]       * e[l];
        float a1 = e[16 + l]  * e[16 + l];
        float a2 = e[32 + l]  * e[32 + l];
        float a3 = e[48 + l]  * e[48 + l];
        float a4 = e[64 + l]  * e[64 + l];
        float a5 = e[80 + l]  * e[80 + l];
        float a6 = e[96 + l]  * e[96 + l];
        float a7 = e[112 + l] * e[112 + l];
        s[l] = ((a0 + a1) + (a2 + a3)) + ((a4 + a5) + (a6 + a7));
    }
    float t1[8];
#pragma unroll
    for (int i = 0; i < 8; ++i) t1[i] = s[i] + s[i + 8];
    float t2[4];
#pragma unroll
    for (int i = 0; i < 4; ++i) t2[i] = t1[i] + t1[i + 4];
    return (t2[0] + t2[2]) + (t2[1] + t2[3]);
}

__global__ __launch_bounds__(64) void npsumsq_kernel(const float* __restrict__ src,
                                                     float* __restrict__ dst) {
    __shared__ float buf[16][257];
    const int tid = threadIdx.x;
    const int r0 = blockIdx.x * 16;
#pragma unroll
    for (int it = 0; it < 16; ++it) {
        int idx = it * 64 + tid;
        int r = idx >> 6, c4 = idx & 63;
        float4 v = ((const float4*)(src + (size_t)(r0 + r) * DIM))[c4];
        buf[r][c4 * 4 + 0] = v.x;
        buf[r][c4 * 4 + 1] = v.y;
        buf[r][c4 * 4 + 2] = v.z;
        buf[r][c4 * 4 + 3] = v.w;
    }
    __syncthreads();
    if (tid < 16) {
        const float* e = buf[tid];
        dst[r0 + tid] = np_block128_sumsq(e) + np_block128_sumsq(e + 128);
    }
}

__global__ void zero_kernel(int* p) { if (threadIdx.x == 0) p[0] = 0; }

// ---------------------------------------------------------------------------
// X -> bf16 hi/lo split into scratch (the z_q output region; rewritten later).
// ---------------------------------------------------------------------------
__global__ __launch_bounds__(256) void xsplit_kernel(const float* __restrict__ x,
                                                     unsigned short* __restrict__ xhi,
                                                     unsigned short* __restrict__ xlo) {
    size_t i = (size_t)blockIdx.x * 256 + threadIdx.x;   // float4 index
    float4 v = ((const float4*)x)[i];
    float e[4] = {v.x, v.y, v.z, v.w};
    ushort4 h, l;
    unsigned short hh[4], ll[4];
#pragma unroll
    for (int k = 0; k < 4; ++k) {
        hh[k] = bf16_rne(e[k]);
        ll[k] = bf16_rne(e[k] - bf16_f32(hh[k]));
    }
    h.x = hh[0]; h.y = hh[1]; h.z = hh[2]; h.w = hh[3];
    l.x = ll[0]; l.y = ll[1]; l.z = ll[2]; l.w = ll[3];
    ((ushort4*)xhi)[i] = h;
    ((ushort4*)xlo)[i] = l;
}

// ---------------------------------------------------------------------------
// wprep: w2 (np tree) + bf16 hi/lo split, 16 codes per 64-thread block.
// ---------------------------------------------------------------------------
__global__ __launch_bounds__(64) void wprep_kernel(const float* __restrict__ w,
                                                   float* __restrict__ w2,
                                                   unsigned short* __restrict__ whi,
                                                   unsigned short* __restrict__ wlo) {
    __shared__ float buf[16][257];
    const int tid = threadIdx.x;
    const int r0 = blockIdx.x * 16;
#pragma unroll
    for (int it = 0; it < 16; ++it) {
        int idx = it * 64 + tid;
        int r = idx >> 6, c4 = idx & 63;
        float4 v = ((const float4*)(w + (size_t)(r0 + r) * DIM))[c4];
        buf[r][c4 * 4 + 0] = v.x;
        buf[r][c4 * 4 + 1] = v.y;
        buf[r][c4 * 4 + 2] = v.z;
        buf[r][c4 * 4 + 3] = v.w;
        ushort4 h, l;
        float e[4] = {v.x, v.y, v.z, v.w};
        unsigned short hh[4], ll[4];
#pragma unroll
        for (int i = 0; i < 4; ++i) {
            hh[i] = bf16_rne(e[i]);
            ll[i] = bf16_rne(e[i] - bf16_f32(hh[i]));
        }
        h.x = hh[0]; h.y = hh[1]; h.z = hh[2]; h.w = hh[3];
        l.x = ll[0]; l.y = ll[1]; l.z = ll[2]; l.w = ll[3];
        size_t g = (size_t)(r0 + r) * (DIM / 4) + c4;
        ((ushort4*)whi)[g] = h;
        ((ushort4*)wlo)[g] = l;
    }
    __syncthreads();
    if (tid < 16) {
        const float* e = buf[tid];
        w2[r0 + tid] = np_block128_sumsq(e) + np_block128_sumsq(e + 128);
    }
}

// ---------------------------------------------------------------------------
// Main: block = 32 rows x 1024 codes; 4 waves each own 256 codes, share rows.
// Score = w2 - 2*dot (x2 dropped: row-constant shift, skew << MARGIN; rescue
// handles near-ties np-exactly). Flagged rows compacted via atomicAdd.
// Fragment mappings verified rounds 7/8/9 (absmax=0).
// ---------------------------------------------------------------------------
__global__ __launch_bounds__(256, 2) void vq_mfma(
    const unsigned short* __restrict__ xhi, const unsigned short* __restrict__ xlo,
    const unsigned short* __restrict__ whi, const unsigned short* __restrict__ wlo,
    const float* __restrict__ w2g, float* __restrict__ zout,
    int* __restrict__ flagcnt, int* __restrict__ flaglist) {
    __shared__ float L1s[4][32], L2s[4][32];
    __shared__ int LIs[4][32];

    const int tid = threadIdx.x;
    const int wave = tid >> 6;
    const int lane = tid & 63;
    const int rowbase = blockIdx.x * 32;
    const int kgrp = (lane >> 4) * 8;

    // ---- A fragments: 2 row-frags x 8 q x (hi,lo), pure 16B loads ----
    s16x8 ahi0[8], alo0[8], ahi1[8], alo1[8];
    {
        const unsigned short* xr0 = xhi + (size_t)(rowbase + (lane & 15)) * DIM + kgrp;
        const unsigned short* xl0 = xlo + (size_t)(rowbase + (lane & 15)) * DIM + kgrp;
#pragma unroll
        for (int q = 0; q < 8; ++q) {
            ahi0[q] = *(const s16x8*)(xr0 + q * 32);
            alo0[q] = *(const s16x8*)(xl0 + q * 32);
            ahi1[q] = *(const s16x8*)(xr0 + 16 * DIM + q * 32);
            alo1[q] = *(const s16x8*)(xl0 + 16 * DIM + q * 32);
        }
    }

    float b1[2][4], b2[2][4];
    int i1[2][4];
#pragma unroll
    for (int rf = 0; rf < 2; ++rf)
#pragma unroll
        for (int j = 0; j < 4; ++j) { b1[rf][j] = INFINITY; b2[rf][j] = INFINITY; i1[rf][j] = 0; }

    for (int ct = 0; ct < 16; ++ct) {
        const int code = wave * 256 + ct * 16 + (lane & 15);
        const unsigned short* bh = whi + (size_t)code * DIM + kgrp;
        const unsigned short* bl = wlo + (size_t)code * DIM + kgrp;
        f32x4v a0hh = {0.f, 0.f, 0.f, 0.f};
        f32x4v a0hl = {0.f, 0.f, 0.f, 0.f};
        f32x4v a0lh = {0.f, 0.f, 0.f, 0.f};
        f32x4v a1hh = {0.f, 0.f, 0.f, 0.f};
        f32x4v a1hl = {0.f, 0.f, 0.f, 0.f};
        f32x4v a1lh = {0.f, 0.f, 0.f, 0.f};
#pragma unroll
        for (int q = 0; q < 8; ++q) {
            s16x8 Bh = *(const s16x8*)(bh + q * 32);
            s16x8 Bl = *(const s16x8*)(bl + q * 32);
            a0hh = __builtin_amdgcn_mfma_f32_16x16x32_bf16(ahi0[q], Bh, a0hh, 0, 0, 0);
            a0hl = __builtin_amdgcn_mfma_f32_16x16x32_bf16(ahi0[q], Bl, a0hl, 0, 0, 0);
            a0lh = __builtin_amdgcn_mfma_f32_16x16x32_bf16(alo0[q], Bh, a0lh, 0, 0, 0);
            a1hh = __builtin_amdgcn_mfma_f32_16x16x32_bf16(ahi1[q], Bh, a1hh, 0, 0, 0);
            a1hl = __builtin_amdgcn_mfma_f32_16x16x32_bf16(ahi1[q], Bl, a1hl, 0, 0, 0);
            a1lh = __builtin_amdgcn_mfma_f32_16x16x32_bf16(alo1[q], Bh, a1lh, 0, 0, 0);
        }
        float w2v = w2g[code];
#pragma unroll
        for (int j = 0; j < 4; ++j) {
            float d0 = (a0hh[j] + a0hl[j]) + a0lh[j];
            float s0 = w2v - 2.0f * d0;
            if (s0 < b2[0][j]) {
                if (s0 < b1[0][j]) { b2[0][j] = b1[0][j]; b1[0][j] = s0; i1[0][j] = code; }
                else b2[0][j] = s0;
            }
            float d1 = (a1hh[j] + a1hl[j]) + a1lh[j];
            float s1 = w2v - 2.0f * d1;
            if (s1 < b2[1][j]) {
                if (s1 < b1[1][j]) { b2[1][j] = b1[1][j]; b1[1][j] = s1; i1[1][j] = code; }
                else b2[1][j] = s1;
            }
        }
    }

    // butterfly top-2 reduce across the 16-lane col group (masks 1,2,4,8)
#pragma unroll
    for (int m = 1; m < 16; m <<= 1) {
#pragma unroll
        for (int rf = 0; rf < 2; ++rf)
#pragma unroll
            for (int j = 0; j < 4; ++j) {
                float ov1 = __shfl_xor(b1[rf][j], m);
                int oi = __shfl_xor(i1[rf][j], m);
                float ov2 = __shfl_xor(b2[rf][j], m);
                float nb2 = fminf(fmaxf(b1[rf][j], ov1), fminf(b2[rf][j], ov2));
                if (ov1 < b1[rf][j] || (ov1 == b1[rf][j] && oi < i1[rf][j])) {
                    b1[rf][j] = ov1; i1[rf][j] = oi;
                }
                b2[rf][j] = nb2;
            }
    }
    if ((lane & 15) == 0) {
#pragma unroll
        for (int rf = 0; rf < 2; ++rf)
#pragma unroll
            for (int j = 0; j < 4; ++j) {
                int r = (lane >> 4) * 4 + j + 16 * rf;
                L1s[wave][r] = b1[rf][j];
                L2s[wave][r] = b2[rf][j];
                LIs[wave][r] = i1[rf][j];
            }
    }
    __syncthreads();

    // merge 4 waves in ascending code order; write zout; flag near-ties
    bool flg = false;
    if (tid < 32) {
        float g1 = INFINITY, g2 = INFINITY;
        int gi = 0;
#pragma unroll
        for (int ww = 0; ww < 4; ++ww) {
            float v1 = L1s[ww][tid], v2 = L2s[ww][tid];
            int vi = LIs[ww][tid];
            float n2 = fminf(fmaxf(g1, v1), fminf(g2, v2));
            if (v1 < g1) { g1 = v1; gi = vi; }
            g2 = n2;
        }
        zout[rowbase + tid] = (float)gi;
        flg = (g2 - g1 < MARGIN);
    }
    unsigned long long bal = __ballot(flg);   // wave 0; bits 0..31 = rows
    if (tid == 0 && (bal & 0xFFFFFFFFull)) {
        unsigned int b = (unsigned int)(bal & 0xFFFFFFFFull);
        while (b) {
            int j = __ffs(b) - 1;
            b &= b - 1;
            int slot = atomicAdd(flagcnt, 1);
            flaglist[slot] = rowbase + j;
        }
    }
}

// ---------------------------------------------------------------------------
// Gather z_q from final indices (runs after ALL vq_mfma blocks — the xhi/xlo
// scratch it overwrites is no longer needed).
// ---------------------------------------------------------------------------
__global__ __launch_bounds__(256) void gather_kernel(const float* __restrict__ zout,
                                                     const float* __restrict__ w,
                                                     float* __restrict__ zq) {
    const int tid = threadIdx.x;
    const int bm0 = blockIdx.x * 16;
    __shared__ int widx[16];
    if (tid < 16) widx[tid] = (int)zout[bm0 + tid];
    __syncthreads();
    const float4* w4 = (const float4*)w;
    float4* zq4 = (float4*)zq;
#pragma unroll
    for (int p = 0; p < 4; ++p) {
        int lin = p * 256 + tid;
        int row = lin >> 6, q = lin & 63;
        zq4[(size_t)(bm0 + row) * 64 + q] = w4[(size_t)widx[row] * 64 + q];
    }
}

// ---------------------------------------------------------------------------
// Exact np-f32 rescore of compacted flagged rows. Same accumulation semantics
// as the round-5-verified kernel (k strictly ascending, single acc, fma) —
// only the LOAD WIDTH is float4 now. Grid-strided: no tail-block serialization.
// ---------------------------------------------------------------------------
__global__ __launch_bounds__(256) void rescue_kernel(
    const float* __restrict__ x, const float* __restrict__ w,
    const float* __restrict__ w2g, const int* __restrict__ flagcnt,
    const int* __restrict__ flaglist, float* __restrict__ zout,
    float* __restrict__ zq) {
    __shared__ __align__(16) float xs[DIM];
    __shared__ float dv[256];
    __shared__ int di[256];
    __shared__ int mi_s;
    __shared__ float x2_s;
    const int tid = threadIdx.x;
    const int cnt = flagcnt[0];
    for (int f = blockIdx.x; f < cnt; f += gridDim.x) {
        const int r = flaglist[f];
        __syncthreads();
        for (int i = tid; i < DIM; i += 256) xs[i] = x[(size_t)r * DIM + i];
        __syncthreads();
        if (tid == 0)
            x2_s = np_block128_sumsq(xs) + np_block128_sumsq(xs + 128);
        __syncthreads();
        const float x2vv = x2_s;
        const float4* xs4 = (const float4*)xs;
        float bv = INFINITY;
        int bi = 0;
#pragma unroll
        for (int cc = 0; cc < 4; ++cc) {
            int c = tid + cc * 256;   // ascending per thread
            const float4* wr4 = (const float4*)(w + (size_t)c * DIM);
            float dot = 0.f;
#pragma unroll
            for (int k4 = 0; k4 < DIM / 4; ++k4) {
                float4 wv = wr4[k4];
                float4 xv = xs4[k4];
                dot = __builtin_fmaf(xv.x, wv.x, dot);
                dot = __builtin_fmaf(xv.y, wv.y, dot);
                dot = __builtin_fmaf(xv.z, wv.z, dot);
                dot = __builtin_fmaf(xv.w, wv.w, dot);
            }
            float s = (x2vv - 2.0f * dot) + w2g[c];
            if (s < bv) { bv = s; bi = c; }
        }
        dv[tid] = bv;
        di[tid] = bi;
        __syncthreads();
        if (tid == 0) {
            float mv = dv[0];
            int mi = di[0];
            for (int t = 1; t < 256; ++t)
                if (dv[t] < mv || (dv[t] == mv && di[t] < mi)) { mv = dv[t]; mi = di[t]; }
            zout[r] = (float)mi;
            mi_s = mi;
        }
        __syncthreads();
        zq[(size_t)r * DIM + tid] = w[(size_t)mi_s * DIM + tid];
    }
}

// ===========================================================================
// Fallback (round-5 passing LDS kernel) if ws is too small. Needs only x2/w2.
// ===========================================================================
#define BM 64
#define BN 128
#define BK 64
#define LDX 68

__global__ __launch_bounds__(256) void vq_kernel_lds(
    const float* __restrict__ x, const float* __restrict__ w,
    const float* __restrict__ x2g, const float* __restrict__ w2g,
    float* __restrict__ zout, float* __restrict__ zq) {
    __shared__ float xs[BM * LDX];
    __shared__ float ws_[BN * LDX];
    __shared__ float sw2[K_CODES];
    __shared__ float sx2[BM];
    __shared__ int widx[BM];

    const int tid = threadIdx.x;
    const int bm0 = blockIdx.x * BM;
    const int rg = tid & 15;
    const int cg = tid >> 4;

    for (int i = tid; i < K_CODES; i += 256) sw2[i] = w2g[i];
    if (tid < BM) sx2[tid] = x2g[bm0 + tid];

    float best[4];
    int bidx[4];
#pragma unroll
    for (int i = 0; i < 4; ++i) { best[i] = INFINITY; bidx[i] = 0; }

    const float4* x4 = (const float4*)x;
    const float4* w4 = (const float4*)w;

    for (int cn = 0; cn < K_CODES / BN; ++cn) {
        float acc[4][8];
#pragma unroll
        for (int i = 0; i < 4; ++i)
#pragma unroll
            for (int j = 0; j < 8; ++j) acc[i][j] = 0.f;

        for (int dk = 0; dk < DIM / BK; ++dk) {
            __syncthreads();
#pragma unroll
            for (int p = 0; p < 4; ++p) {
                int l = p * 256 + tid;
                int row = l >> 4, c4 = l & 15;
                float4 v = x4[(size_t)(bm0 + row) * (DIM / 4) + dk * (BK / 4) + c4];
                *(float4*)&xs[row * LDX + c4 * 4] = v;
            }
#pragma unroll
            for (int p = 0; p < 8; ++p) {
                int l = p * 256 + tid;
                int row = l >> 4, c4 = l & 15;
                float4 v = w4[(size_t)(cn * BN + row) * (DIM / 4) + dk * (BK / 4) + c4];
                *(float4*)&ws_[row * LDX + c4 * 4] = v;
            }
            __syncthreads();
#pragma unroll
            for (int d = 0; d < BK; d += 4) {
                float4 xv[4], wv[8];
#pragma unroll
                for (int i = 0; i < 4; ++i)
                    xv[i] = *(const float4*)&xs[(rg + 16 * i) * LDX + d];
#pragma unroll
                for (int j = 0; j < 8; ++j)
                    wv[j] = *(const float4*)&ws_[(cg + 16 * j) * LDX + d];
#pragma unroll
                for (int i = 0; i < 4; ++i)
#pragma unroll
                    for (int j = 0; j < 8; ++j) {
                        acc[i][j] = __builtin_fmaf(xv[i].x, wv[j].x, acc[i][j]);
                        acc[i][j] = __builtin_fmaf(xv[i].y, wv[j].y, acc[i][j]);
                        acc[i][j] = __builtin_fmaf(xv[i].z, wv[j].z, acc[i][j]);
                        acc[i][j] = __builtin_fmaf(xv[i].w, wv[j].w, acc[i][j]);
                    }
            }
        }
#pragma unroll
        for (int j = 0; j < 8; ++j) {
            int c = cn * BN + cg + 16 * j;
            float w2v = sw2[c];
#pragma unroll
            for (int i = 0; i < 4; ++i) {
                float t = sx2[rg + 16 * i] - 2.0f * acc[i][j];
                float s = t + w2v;
                if (s < best[i]) { best[i] = s; bidx[i] = c; }
            }
        }
    }

    __syncthreads();
    float* sval = xs;
    int* sidx = (int*)(xs + 64 * 17);
#pragma unroll
    for (int i = 0; i < 4; ++i) {
        sval[(rg + 16 * i) * 17 + cg] = best[i];
        sidx[(rg + 16 * i) * 17 + cg] = bidx[i];
    }
    __syncthreads();
    if (tid < BM) {
        float bv = INFINITY;
        int bi = 0;
        for (int c = 0; c < 16; ++c) {
            float v = sval[tid * 17 + c];
            int id = sidx[tid * 17 + c];
            if (v < bv || (v == bv && id < bi)) { bv = v; bi = id; }
        }
        widx[tid] = bi;
        zout[bm0 + tid] = (float)bi;
    }
    __syncthreads();
    float4* zq4 = (float4*)zq;
#pragma unroll
    for (int p = 0; p < 16; ++p) {
        int lin = p * 256 + tid;
        int row = lin >> 6, q = lin & 63;
        zq4[(size_t)(bm0 + row) * 64 + q] = w4[(size_t)widx[row] * 64 + q];
    }
}

extern "C" void kernel_launch(void* const* d_in, const int* in_sizes, int n_in,
                              void* d_out, int out_size, void* d_ws, size_t ws_size,
                              hipStream_t stream) {
    const float* z_e = (const float*)d_in[0];
    const float* emb = (const float*)d_in[1];
    float* x2g = (float*)d_ws;                                   // fallback x2
    int* flaglist = (int*)d_ws;                                  // MFMA path [32768]
    float* w2g = x2g + N_ROWS;                                   // [1024]
    unsigned short* whi = (unsigned short*)(w2g + K_CODES);      // [262144]
    unsigned short* wlo = whi + (size_t)K_CODES * DIM;           // [262144]
    int* flagcnt = (int*)(wlo + (size_t)K_CODES * DIM);          // [1]
    float* zout = (float*)d_out;                                 // [32768]
    float* zq = (float*)d_out + N_ROWS;                          // [32768*256]
    // X hi/lo scratch lives in the zq region (exactly 32 MB); gather (after
    // all vq_mfma blocks) and rescue rewrite every byte of zq afterwards.
    unsigned short* xhi = (unsigned short*)zq;                   // 16 MB
    unsigned short* xlo = xhi + (size_t)N_ROWS * DIM;            // 16 MB

    if (ws_size >= WS_NEEDED) {
        zero_kernel<<<1, 64, 0, stream>>>(flagcnt);
        xsplit_kernel<<<N_ROWS * DIM / 4 / 256, 256, 0, stream>>>(z_e, xhi, xlo);
        wprep_kernel<<<K_CODES / 16, 64, 0, stream>>>(emb, w2g, whi, wlo);
        vq_mfma<<<N_ROWS / 32, 256, 0, stream>>>(xhi, xlo, whi, wlo, w2g,
                                                 zout, flagcnt, flaglist);
        gather_kernel<<<N_ROWS / 16, 256, 0, stream>>>(zout, emb, zq);
        rescue_kernel<<<256, 256, 0, stream>>>(z_e, emb, w2g, flagcnt,
                                               flaglist, zout, zq);
    } else {
        npsumsq_kernel<<<N_ROWS / 16, 64, 0, stream>>>(z_e, x2g);
        npsumsq_kernel<<<K_CODES / 16, 64, 0, stream>>>(emb, w2g);
        vq_kernel_lds<<<N_ROWS / BM, 256, 0, stream>>>(z_e, emb, x2g, w2g, zout, zq);
    }
}

// Round 11
// 223.209 us; speedup vs baseline: 1.4531x; 1.4531x over previous
//
#include <hip/hip_runtime.h>
#include <math.h>

#define N_ROWS 32768
#define DIM 256
#define K_CODES 1024
#define MARGIN 2e-3f

typedef float f32x4v __attribute__((ext_vector_type(4)));
typedef short s16x8 __attribute__((ext_vector_type(8)));

// ---- ws layout (bytes) ----
// flaglist int[32768]     @ 0          (MFMA path; fallback uses as x2 floats)
// w2       float[1024]    @ 131072
// whi      ushort[262144] @ 135168
// wlo      ushort[262144] @ 659456
// flagcnt  int            @ 1183744
#define WS_NEEDED ((size_t)1183748)

__device__ __forceinline__ unsigned short bf16_rne(float f) {
    unsigned int u = __float_as_uint(f);
    unsigned int r = (u + 0x7FFFu + ((u >> 16) & 1u)) >> 16;
    return (unsigned short)r;
}
__device__ __forceinline__ float bf16_f32(unsigned short h) {
    return __uint_as_float(((unsigned int)h) << 16);
}

// ---------------------------------------------------------------------------
// numpy-replica pairwise sum of squares (AVX512 path) — bitwise == np.sum(x*x)
// ---------------------------------------------------------------------------
__device__ __forceinline__ float np_block128_sumsq(const float* e) {
#pragma clang fp contract(off)
    float s[16];
#pragma unroll
    for (int l = 0; l < 16; ++l) {
        float a0 = e[l]       * e[l];
        float a1 = e[16 + l]  * e[16 + l];
        float a2 = e[32 + l]  * e[32 + l];
        float a3 = e[48 + l]  * e[48 + l];
        float a4 = e[64 + l]  * e[64 + l];
        float a5 = e[80 + l]  * e[80 + l];
        float a6 = e[96 + l]  * e[96 + l];
        float a7 = e[112 + l] * e[112 + l];
        s[l] = ((a0 + a1) + (a2 + a3)) + ((a4 + a5) + (a6 + a7));
    }
    float t1[8];
#pragma unroll
    for (int i = 0; i < 8; ++i) t1[i] = s[i] + s[i + 8];
    float t2[4];
#pragma unroll
    for (int i = 0; i < 4; ++i) t2[i] = t1[i] + t1[i + 4];
    return (t2[0] + t2[2]) + (t2[1] + t2[3]);
}

__global__ __launch_bounds__(64) void npsumsq_kernel(const float* __restrict__ src,
                                                     float* __restrict__ dst) {
    __shared__ float buf[16][257];
    const int tid = threadIdx.x;
    const int r0 = blockIdx.x * 16;
#pragma unroll
    for (int it = 0; it < 16; ++it) {
        int idx = it * 64 + tid;
        int r = idx >> 6, c4 = idx & 63;
        float4 v = ((const float4*)(src + (size_t)(r0 + r) * DIM))[c4];
        buf[r][c4 * 4 + 0] = v.x;
        buf[r][c4 * 4 + 1] = v.y;
        buf[r][c4 * 4 + 2] = v.z;
        buf[r][c4 * 4 + 3] = v.w;
    }
    __syncthreads();
    if (tid < 16) {
        const float* e = buf[tid];
        dst[r0 + tid] = np_block128_sumsq(e) + np_block128_sumsq(e + 128);
    }
}

__global__ void zero_kernel(int* p) { if (threadIdx.x == 0) p[0] = 0; }

// ---------------------------------------------------------------------------
// X -> bf16 hi/lo split into scratch (the z_q output region; rewritten later).
// ---------------------------------------------------------------------------
__global__ __launch_bounds__(256) void xsplit_kernel(const float* __restrict__ x,
                                                     unsigned short* __restrict__ xhi,
                                                     unsigned short* __restrict__ xlo) {
    size_t i = (size_t)blockIdx.x * 256 + threadIdx.x;   // float4 index
    float4 v = ((const float4*)x)[i];
    float e[4] = {v.x, v.y, v.z, v.w};
    ushort4 h, l;
    unsigned short hh[4], ll[4];
#pragma unroll
    for (int k = 0; k < 4; ++k) {
        hh[k] = bf16_rne(e[k]);
        ll[k] = bf16_rne(e[k] - bf16_f32(hh[k]));
    }
    h.x = hh[0]; h.y = hh[1]; h.z = hh[2]; h.w = hh[3];
    l.x = ll[0]; l.y = ll[1]; l.z = ll[2]; l.w = ll[3];
    ((ushort4*)xhi)[i] = h;
    ((ushort4*)xlo)[i] = l;
}

// ---------------------------------------------------------------------------
// wprep: w2 (np tree) + bf16 hi/lo split, 16 codes per 64-thread block.
// ---------------------------------------------------------------------------
__global__ __launch_bounds__(64) void wprep_kernel(const float* __restrict__ w,
                                                   float* __restrict__ w2,
                                                   unsigned short* __restrict__ whi,
                                                   unsigned short* __restrict__ wlo) {
    __shared__ float buf[16][257];
    const int tid = threadIdx.x;
    const int r0 = blockIdx.x * 16;
#pragma unroll
    for (int it = 0; it < 16; ++it) {
        int idx = it * 64 + tid;
        int r = idx >> 6, c4 = idx & 63;
        float4 v = ((const float4*)(w + (size_t)(r0 + r) * DIM))[c4];
        buf[r][c4 * 4 + 0] = v.x;
        buf[r][c4 * 4 + 1] = v.y;
        buf[r][c4 * 4 + 2] = v.z;
        buf[r][c4 * 4 + 3] = v.w;
        ushort4 h, l;
        float e[4] = {v.x, v.y, v.z, v.w};
        unsigned short hh[4], ll[4];
#pragma unroll
        for (int i = 0; i < 4; ++i) {
            hh[i] = bf16_rne(e[i]);
            ll[i] = bf16_rne(e[i] - bf16_f32(hh[i]));
        }
        h.x = hh[0]; h.y = hh[1]; h.z = hh[2]; h.w = hh[3];
        l.x = ll[0]; l.y = ll[1]; l.z = ll[2]; l.w = ll[3];
        size_t g = (size_t)(r0 + r) * (DIM / 4) + c4;
        ((ushort4*)whi)[g] = h;
        ((ushort4*)wlo)[g] = l;
    }
    __syncthreads();
    if (tid < 16) {
        const float* e = buf[tid];
        w2[r0 + tid] = np_block128_sumsq(e) + np_block128_sumsq(e + 128);
    }
}

// ---------------------------------------------------------------------------
// Main: block = 32 rows x 1024 codes; 4 waves each own 256 codes, share rows.
// Score = w2 - 2*dot (x2 dropped: row-constant shift, skew << MARGIN; rescue
// handles near-ties np-exactly). Flagged rows compacted via atomicAdd.
// Fragment mappings verified rounds 7/8/9 (absmax=0).
// ---------------------------------------------------------------------------
__global__ __launch_bounds__(256, 2) void vq_mfma(
    const unsigned short* __restrict__ xhi, const unsigned short* __restrict__ xlo,
    const unsigned short* __restrict__ whi, const unsigned short* __restrict__ wlo,
    const float* __restrict__ w2g, float* __restrict__ zout,
    int* __restrict__ flagcnt, int* __restrict__ flaglist) {
    __shared__ float L1s[4][32], L2s[4][32];
    __shared__ int LIs[4][32];

    const int tid = threadIdx.x;
    const int wave = tid >> 6;
    const int lane = tid & 63;
    const int rowbase = blockIdx.x * 32;
    const int kgrp = (lane >> 4) * 8;

    // ---- A fragments: 2 row-frags x 8 q x (hi,lo), pure 16B loads ----
    s16x8 ahi0[8], alo0[8], ahi1[8], alo1[8];
    {
        const unsigned short* xr0 = xhi + (size_t)(rowbase + (lane & 15)) * DIM + kgrp;
        const unsigned short* xl0 = xlo + (size_t)(rowbase + (lane & 15)) * DIM + kgrp;
#pragma unroll
        for (int q = 0; q < 8; ++q) {
            ahi0[q] = *(const s16x8*)(xr0 + q * 32);
            alo0[q] = *(const s16x8*)(xl0 + q * 32);
            ahi1[q] = *(const s16x8*)(xr0 + 16 * DIM + q * 32);
            alo1[q] = *(const s16x8*)(xl0 + 16 * DIM + q * 32);
        }
    }

    float b1[2][4], b2[2][4];
    int i1[2][4];
#pragma unroll
    for (int rf = 0; rf < 2; ++rf)
#pragma unroll
        for (int j = 0; j < 4; ++j) { b1[rf][j] = INFINITY; b2[rf][j] = INFINITY; i1[rf][j] = 0; }

    for (int ct = 0; ct < 16; ++ct) {
        const int code = wave * 256 + ct * 16 + (lane & 15);
        const unsigned short* bh = whi + (size_t)code * DIM + kgrp;
        const unsigned short* bl = wlo + (size_t)code * DIM + kgrp;
        f32x4v a0hh = {0.f, 0.f, 0.f, 0.f};
        f32x4v a0hl = {0.f, 0.f, 0.f, 0.f};
        f32x4v a0lh = {0.f, 0.f, 0.f, 0.f};
        f32x4v a1hh = {0.f, 0.f, 0.f, 0.f};
        f32x4v a1hl = {0.f, 0.f, 0.f, 0.f};
        f32x4v a1lh = {0.f, 0.f, 0.f, 0.f};
#pragma unroll
        for (int q = 0; q < 8; ++q) {
            s16x8 Bh = *(const s16x8*)(bh + q * 32);
            s16x8 Bl = *(const s16x8*)(bl + q * 32);
            a0hh = __builtin_amdgcn_mfma_f32_16x16x32_bf16(ahi0[q], Bh, a0hh, 0, 0, 0);
            a0hl = __builtin_amdgcn_mfma_f32_16x16x32_bf16(ahi0[q], Bl, a0hl, 0, 0, 0);
            a0lh = __builtin_amdgcn_mfma_f32_16x16x32_bf16(alo0[q], Bh, a0lh, 0, 0, 0);
            a1hh = __builtin_amdgcn_mfma_f32_16x16x32_bf16(ahi1[q], Bh, a1hh, 0, 0, 0);
            a1hl = __builtin_amdgcn_mfma_f32_16x16x32_bf16(ahi1[q], Bl, a1hl, 0, 0, 0);
            a1lh = __builtin_amdgcn_mfma_f32_16x16x32_bf16(alo1[q], Bh, a1lh, 0, 0, 0);
        }
        float w2v = w2g[code];
#pragma unroll
        for (int j = 0; j < 4; ++j) {
            float d0 = (a0hh[j] + a0hl[j]) + a0lh[j];
            float s0 = w2v - 2.0f * d0;
            if (s0 < b2[0][j]) {
                if (s0 < b1[0][j]) { b2[0][j] = b1[0][j]; b1[0][j] = s0; i1[0][j] = code; }
                else b2[0][j] = s0;
            }
            float d1 = (a1hh[j] + a1hl[j]) + a1lh[j];
            float s1 = w2v - 2.0f * d1;
            if (s1 < b2[1][j]) {
                if (s1 < b1[1][j]) { b2[1][j] = b1[1][j]; b1[1][j] = s1; i1[1][j] = code; }
                else b2[1][j] = s1;
            }
        }
    }

    // butterfly top-2 reduce across the 16-lane col group (masks 1,2,4,8)
#pragma unroll
    for (int m = 1; m < 16; m <<= 1) {
#pragma unroll
        for (int rf = 0; rf < 2; ++rf)
#pragma unroll
            for (int j = 0; j < 4; ++j) {
                float ov1 = __shfl_xor(b1[rf][j], m);
                int oi = __shfl_xor(i1[rf][j], m);
                float ov2 = __shfl_xor(b2[rf][j], m);
                float nb2 = fminf(fmaxf(b1[rf][j], ov1), fminf(b2[rf][j], ov2));
                if (ov1 < b1[rf][j] || (ov1 == b1[rf][j] && oi < i1[rf][j])) {
                    b1[rf][j] = ov1; i1[rf][j] = oi;
                }
                b2[rf][j] = nb2;
            }
    }
    if ((lane & 15) == 0) {
#pragma unroll
        for (int rf = 0; rf < 2; ++rf)
#pragma unroll
            for (int j = 0; j < 4; ++j) {
                int r = (lane >> 4) * 4 + j + 16 * rf;
                L1s[wave][r] = b1[rf][j];
                L2s[wave][r] = b2[rf][j];
                LIs[wave][r] = i1[rf][j];
            }
    }
    __syncthreads();

    // merge 4 waves in ascending code order; write zout; flag near-ties
    bool flg = false;
    if (tid < 32) {
        float g1 = INFINITY, g2 = INFINITY;
        int gi = 0;
#pragma unroll
        for (int ww = 0; ww < 4; ++ww) {
            float v1 = L1s[ww][tid], v2 = L2s[ww][tid];
            int vi = LIs[ww][tid];
            float n2 = fminf(fmaxf(g1, v1), fminf(g2, v2));
            if (v1 < g1) { g1 = v1; gi = vi; }
            g2 = n2;
        }
        zout[rowbase + tid] = (float)gi;
        flg = (g2 - g1 < MARGIN);
    }
    unsigned long long bal = __ballot(flg);   // wave 0; bits 0..31 = rows
    if (tid == 0 && (bal & 0xFFFFFFFFull)) {
        unsigned int b = (unsigned int)(bal & 0xFFFFFFFFull);
        while (b) {
            int j = __ffs(b) - 1;
            b &= b - 1;
            int slot = atomicAdd(flagcnt, 1);
            flaglist[slot] = rowbase + j;
        }
    }
}

// ---------------------------------------------------------------------------
// Gather z_q from final indices (runs after ALL vq_mfma blocks — the xhi/xlo
// scratch it overwrites is no longer needed).
// ---------------------------------------------------------------------------
__global__ __launch_bounds__(256) void gather_kernel(const float* __restrict__ zout,
                                                     const float* __restrict__ w,
                                                     float* __restrict__ zq) {
    const int tid = threadIdx.x;
    const int bm0 = blockIdx.x * 16;
    __shared__ int widx[16];
    if (tid < 16) widx[tid] = (int)zout[bm0 + tid];
    __syncthreads();
    const float4* w4 = (const float4*)w;
    float4* zq4 = (float4*)zq;
#pragma unroll
    for (int p = 0; p < 4; ++p) {
        int lin = p * 256 + tid;
        int row = lin >> 6, q = lin & 63;
        zq4[(size_t)(bm0 + row) * 64 + q] = w4[(size_t)widx[row] * 64 + q];
    }
}

// ---------------------------------------------------------------------------
// Exact np-f32 rescore of compacted flagged rows. Accumulation semantics
// identical to the round-5-verified kernel (k strictly ascending, single acc
// per dot, fma). k4-outer/cc-inner: live set = 1 xv + 4 wv + 4 acc -> no
// spill (round 10 lesson: full unroll hoisted 256 loads -> 167 MB scratch).
// ---------------------------------------------------------------------------
__global__ __launch_bounds__(256) void rescue_kernel(
    const float* __restrict__ x, const float* __restrict__ w,
    const float* __restrict__ w2g, const int* __restrict__ flagcnt,
    const int* __restrict__ flaglist, float* __restrict__ zout,
    float* __restrict__ zq) {
    __shared__ __align__(16) float xs[DIM];
    __shared__ float dv[256];
    __shared__ int di[256];
    __shared__ int mi_s;
    __shared__ float x2_s;
    const int tid = threadIdx.x;
    const int cnt = flagcnt[0];
    for (int f = blockIdx.x; f < cnt; f += gridDim.x) {
        const int r = flaglist[f];
        __syncthreads();
        for (int i = tid; i < DIM; i += 256) xs[i] = x[(size_t)r * DIM + i];
        __syncthreads();
        if (tid == 0)
            x2_s = np_block128_sumsq(xs) + np_block128_sumsq(xs + 128);
        __syncthreads();
        const float x2vv = x2_s;
        const float4* xs4 = (const float4*)xs;
        const float4* wr0 = (const float4*)(w + (size_t)(tid + 0 * 256) * DIM);
        const float4* wr1 = (const float4*)(w + (size_t)(tid + 1 * 256) * DIM);
        const float4* wr2 = (const float4*)(w + (size_t)(tid + 2 * 256) * DIM);
        const float4* wr3 = (const float4*)(w + (size_t)(tid + 3 * 256) * DIM);
        float acc0 = 0.f, acc1 = 0.f, acc2 = 0.f, acc3 = 0.f;
#pragma unroll 4
        for (int k4 = 0; k4 < DIM / 4; ++k4) {
            float4 xv = xs4[k4];
            float4 w0 = wr0[k4], w1 = wr1[k4], w2 = wr2[k4], w3 = wr3[k4];
            acc0 = __builtin_fmaf(xv.x, w0.x, acc0);
            acc0 = __builtin_fmaf(xv.y, w0.y, acc0);
            acc0 = __builtin_fmaf(xv.z, w0.z, acc0);
            acc0 = __builtin_fmaf(xv.w, w0.w, acc0);
            acc1 = __builtin_fmaf(xv.x, w1.x, acc1);
            acc1 = __builtin_fmaf(xv.y, w1.y, acc1);
            acc1 = __builtin_fmaf(xv.z, w1.z, acc1);
            acc1 = __builtin_fmaf(xv.w, w1.w, acc1);
            acc2 = __builtin_fmaf(xv.x, w2.x, acc2);
            acc2 = __builtin_fmaf(xv.y, w2.y, acc2);
            acc2 = __builtin_fmaf(xv.z, w2.z, acc2);
            acc2 = __builtin_fmaf(xv.w, w2.w, acc2);
            acc3 = __builtin_fmaf(xv.x, w3.x, acc3);
            acc3 = __builtin_fmaf(xv.y, w3.y, acc3);
            acc3 = __builtin_fmaf(xv.z, w3.z, acc3);
            acc3 = __builtin_fmaf(xv.w, w3.w, acc3);
        }
        float bv = INFINITY;
        int bi = 0;
        float accs[4] = {acc0, acc1, acc2, acc3};
#pragma unroll
        for (int cc = 0; cc < 4; ++cc) {
            int c = tid + cc * 256;   // cc ascending -> c ascending per thread
            float s = (x2vv - 2.0f * accs[cc]) + w2g[c];
            if (s < bv) { bv = s; bi = c; }
        }
        dv[tid] = bv;
        di[tid] = bi;
        __syncthreads();
        if (tid == 0) {
            float mv = dv[0];
            int mi = di[0];
            for (int t = 1; t < 256; ++t)
                if (dv[t] < mv || (dv[t] == mv && di[t] < mi)) { mv = dv[t]; mi = di[t]; }
            zout[r] = (float)mi;
            mi_s = mi;
        }
        __syncthreads();
        zq[(size_t)r * DIM + tid] = w[(size_t)mi_s * DIM + tid];
    }
}

// ===========================================================================
// Fallback (round-5 passing LDS kernel) if ws is too small. Needs only x2/w2.
// ===========================================================================
#define BM 64
#define BN 128
#define BK 64
#define LDX 68

__global__ __launch_bounds__(256) void vq_kernel_lds(
    const float* __restrict__ x, const float* __restrict__ w,
    const float* __restrict__ x2g, const float* __restrict__ w2g,
    float* __restrict__ zout, float* __restrict__ zq) {
    __shared__ float xs[BM * LDX];
    __shared__ float ws_[BN * LDX];
    __shared__ float sw2[K_CODES];
    __shared__ float sx2[BM];
    __shared__ int widx[BM];

    const int tid = threadIdx.x;
    const int bm0 = blockIdx.x * BM;
    const int rg = tid & 15;
    const int cg = tid >> 4;

    for (int i = tid; i < K_CODES; i += 256) sw2[i] = w2g[i];
    if (tid < BM) sx2[tid] = x2g[bm0 + tid];

    float best[4];
    int bidx[4];
#pragma unroll
    for (int i = 0; i < 4; ++i) { best[i] = INFINITY; bidx[i] = 0; }

    const float4* x4 = (const float4*)x;
    const float4* w4 = (const float4*)w;

    for (int cn = 0; cn < K_CODES / BN; ++cn) {
        float acc[4][8];
#pragma unroll
        for (int i = 0; i < 4; ++i)
#pragma unroll
            for (int j = 0; j < 8; ++j) acc[i][j] = 0.f;

        for (int dk = 0; dk < DIM / BK; ++dk) {
            __syncthreads();
#pragma unroll
            for (int p = 0; p < 4; ++p) {
                int l = p * 256 + tid;
                int row = l >> 4, c4 = l & 15;
                float4 v = x4[(size_t)(bm0 + row) * (DIM / 4) + dk * (BK / 4) + c4];
                *(float4*)&xs[row * LDX + c4 * 4] = v;
            }
#pragma unroll
            for (int p = 0; p < 8; ++p) {
                int l = p * 256 + tid;
                int row = l >> 4, c4 = l & 15;
                float4 v = w4[(size_t)(cn * BN + row) * (DIM / 4) + dk * (BK / 4) + c4];
                *(float4*)&ws_[row * LDX + c4 * 4] = v;
            }
            __syncthreads();
#pragma unroll
            for (int d = 0; d < BK; d += 4) {
                float4 xv[4], wv[8];
#pragma unroll
                for (int i = 0; i < 4; ++i)
                    xv[i] = *(const float4*)&xs[(rg + 16 * i) * LDX + d];
#pragma unroll
                for (int j = 0; j < 8; ++j)
                    wv[j] = *(const float4*)&ws_[(cg + 16 * j) * LDX + d];
#pragma unroll
                for (int i = 0; i < 4; ++i)
#pragma unroll
                    for (int j = 0; j < 8; ++j) {
                        acc[i][j] = __builtin_fmaf(xv[i].x, wv[j].x, acc[i][j]);
                        acc[i][j] = __builtin_fmaf(xv[i].y, wv[j].y, acc[i][j]);
                        acc[i][j] = __builtin_fmaf(xv[i].z, wv[j].z, acc[i][j]);
                        acc[i][j] = __builtin_fmaf(xv[i].w, wv[j].w, acc[i][j]);
                    }
            }
        }
#pragma unroll
        for (int j = 0; j < 8; ++j) {
            int c = cn * BN + cg + 16 * j;
            float w2v = sw2[c];
#pragma unroll
            for (int i = 0; i < 4; ++i) {
                float t = sx2[rg + 16 * i] - 2.0f * acc[i][j];
                float s = t + w2v;
                if (s < best[i]) { best[i] = s; bidx[i] = c; }
            }
        }
    }

    __syncthreads();
    float* sval = xs;
    int* sidx = (int*)(xs + 64 * 17);
#pragma unroll
    for (int i = 0; i < 4; ++i) {
        sval[(rg + 16 * i) * 17 + cg] = best[i];
        sidx[(rg + 16 * i) * 17 + cg] = bidx[i];
    }
    __syncthreads();
    if (tid < BM) {
        float bv = INFINITY;
        int bi = 0;
        for (int c = 0; c < 16; ++c) {
            float v = sval[tid * 17 + c];
            int id = sidx[tid * 17 + c];
            if (v < bv || (v == bv && id < bi)) { bv = v; bi = id; }
        }
        widx[tid] = bi;
        zout[bm0 + tid] = (float)bi;
    }
    __syncthreads();
    float4* zq4 = (float4*)zq;
#pragma unroll
    for (int p = 0; p < 16; ++p) {
        int lin = p * 256 + tid;
        int row = lin >> 6, q = lin & 63;
        zq4[(size_t)(bm0 + row) * 64 + q] = w4[(size_t)widx[row] * 64 + q];
    }
}

extern "C" void kernel_launch(void* const* d_in, const int* in_sizes, int n_in,
                              void* d_out, int out_size, void* d_ws, size_t ws_size,
                              hipStream_t stream) {
    const float* z_e = (const float*)d_in[0];
    const float* emb = (const float*)d_in[1];
    float* x2g = (float*)d_ws;                                   // fallback x2
    int* flaglist = (int*)d_ws;                                  // MFMA path [32768]
    float* w2g = x2g + N_ROWS;                                   // [1024]
    unsigned short* whi = (unsigned short*)(w2g + K_CODES);      // [262144]
    unsigned short* wlo = whi + (size_t)K_CODES * DIM;           // [262144]
    int* flagcnt = (int*)(wlo + (size_t)K_CODES * DIM);          // [1]
    float* zout = (float*)d_out;                                 // [32768]
    float* zq = (float*)d_out + N_ROWS;                          // [32768*256]
    // X hi/lo scratch lives in the zq region (exactly 32 MB); gather (after
    // all vq_mfma blocks) and rescue rewrite every byte of zq afterwards.
    unsigned short* xhi = (unsigned short*)zq;                   // 16 MB
    unsigned short* xlo = xhi + (size_t)N_ROWS * DIM;            // 16 MB

    if (ws_size >= WS_NEEDED) {
        zero_kernel<<<1, 64, 0, stream>>>(flagcnt);
        xsplit_kernel<<<N_ROWS * DIM / 4 / 256, 256, 0, stream>>>(z_e, xhi, xlo);
        wprep_kernel<<<K_CODES / 16, 64, 0, stream>>>(emb, w2g, whi, wlo);
        vq_mfma<<<N_ROWS / 32, 256, 0, stream>>>(xhi, xlo, whi, wlo, w2g,
                                                 zout, flagcnt, flaglist);
        gather_kernel<<<N_ROWS / 16, 256, 0, stream>>>(zout, emb, zq);
        rescue_kernel<<<256, 256, 0, stream>>>(z_e, emb, w2g, flagcnt,
                                               flaglist, zout, zq);
    } else {
        npsumsq_kernel<<<N_ROWS / 16, 64, 0, stream>>>(z_e, x2g);
        npsumsq_kernel<<<K_CODES / 16, 64, 0, stream>>>(emb, w2g);
        vq_kernel_lds<<<N_ROWS / BM, 256, 0, stream>>>(z_e, emb, x2g, w2g, zout, zq);
    }
}

// Round 12
// 150.602 us; speedup vs baseline: 2.1536x; 1.4821x over previous
//
#include <hip/hip_runtime.h>
#include <math.h>

#define N_ROWS 32768
#define DIM 256
#define K_CODES 1024
#define MARGIN 2e-3f

typedef float f32x4v __attribute__((ext_vector_type(4)));
typedef short s16x8 __attribute__((ext_vector_type(8)));

// ---- ws layout (bytes) ----
// flaglist int[32768]       @ 0        (fallback uses as x2 floats)
// w2       float[1024]      @ 131072
// wfrag    ushort[524288]   @ 135168   (64 tiles x 16KB, fragment-major)
// flagcnt  int              @ 1183744
#define WS_NEEDED ((size_t)1183748)

__device__ __forceinline__ unsigned short bf16_rne(float f) {
    unsigned int u = __float_as_uint(f);
    unsigned int r = (u + 0x7FFFu + ((u >> 16) & 1u)) >> 16;
    return (unsigned short)r;
}
__device__ __forceinline__ float bf16_f32(unsigned short h) {
    return __uint_as_float(((unsigned int)h) << 16);
}

// ---------------------------------------------------------------------------
// numpy-replica pairwise sum of squares (AVX512 path) — bitwise == np.sum(x*x)
// ---------------------------------------------------------------------------
__device__ __forceinline__ float np_block128_sumsq(const float* e) {
#pragma clang fp contract(off)
    float s[16];
#pragma unroll
    for (int l = 0; l < 16; ++l) {
        float a0 = e[l]       * e[l];
        float a1 = e[16 + l]  * e[16 + l];
        float a2 = e[32 + l]  * e[32 + l];
        float a3 = e[48 + l]  * e[48 + l];
        float a4 = e[64 + l]  * e[64 + l];
        float a5 = e[80 + l]  * e[80 + l];
        float a6 = e[96 + l]  * e[96 + l];
        float a7 = e[112 + l] * e[112 + l];
        s[l] = ((a0 + a1) + (a2 + a3)) + ((a4 + a5) + (a6 + a7));
    }
    float t1[8];
#pragma unroll
    for (int i = 0; i < 8; ++i) t1[i] = s[i] + s[i + 8];
    float t2[4];
#pragma unroll
    for (int i = 0; i < 4; ++i) t2[i] = t1[i] + t1[i + 4];
    return (t2[0] + t2[2]) + (t2[1] + t2[3]);
}

__global__ __launch_bounds__(64) void npsumsq_kernel(const float* __restrict__ src,
                                                     float* __restrict__ dst) {
    __shared__ float buf[16][257];
    const int tid = threadIdx.x;
    const int r0 = blockIdx.x * 16;
#pragma unroll
    for (int it = 0; it < 16; ++it) {
        int idx = it * 64 + tid;
        int r = idx >> 6, c4 = idx & 63;
        float4 v = ((const float4*)(src + (size_t)(r0 + r) * DIM))[c4];
        buf[r][c4 * 4 + 0] = v.x;
        buf[r][c4 * 4 + 1] = v.y;
        buf[r][c4 * 4 + 2] = v.z;
        buf[r][c4 * 4 + 3] = v.w;
    }
    __syncthreads();
    if (tid < 16) {
        const float* e = buf[tid];
        dst[r0 + tid] = np_block128_sumsq(e) + np_block128_sumsq(e + 128);
    }
}

__global__ void zero_kernel(int* p) { if (threadIdx.x == 0) p[0] = 0; }

// ---------------------------------------------------------------------------
// wprep: per 16-code tile, compute w2 (np tree) and write bf16 hi/lo splits in
// FRAGMENT-MAJOR layout: tile t = 16384 B; hi frag bytes q*1024 + lane*16
// hold w[t*16 + (lane&15)][q*32 + (lane>>4)*8 + i]; lo at +8192 B.
// Staging and ds_read in vq_mfma are then fully sequential.
// ---------------------------------------------------------------------------
__global__ __launch_bounds__(64) void wprep_kernel(const float* __restrict__ w,
                                                   float* __restrict__ w2,
                                                   unsigned short* __restrict__ wfrag) {
    __shared__ float buf[16][257];
    const int lane = threadIdx.x;
    const int t = blockIdx.x;
    const int r0 = t * 16;
#pragma unroll
    for (int it = 0; it < 16; ++it) {
        int idx = it * 64 + lane;
        int r = idx >> 6, c4 = idx & 63;
        float4 v = ((const float4*)(w + (size_t)(r0 + r) * DIM))[c4];
        buf[r][c4 * 4 + 0] = v.x;
        buf[r][c4 * 4 + 1] = v.y;
        buf[r][c4 * 4 + 2] = v.z;
        buf[r][c4 * 4 + 3] = v.w;
    }
    __syncthreads();
    if (lane < 16) {
        const float* e = buf[lane];
        w2[r0 + lane] = np_block128_sumsq(e) + np_block128_sumsq(e + 128);
    }
    const int c = lane & 15, ko = lane >> 4;
#pragma unroll
    for (int q = 0; q < 8; ++q) {
        s16x8 hh, ll;
#pragma unroll
        for (int i = 0; i < 8; ++i) {
            float f = buf[c][q * 32 + ko * 8 + i];
            unsigned short h = bf16_rne(f);
            hh[i] = (short)h;
            ll[i] = (short)bf16_rne(f - bf16_f32(h));
        }
        // ushort offsets: tile = 8192, q-block = 512, lane frag = 8
        unsigned short* dh = wfrag + (size_t)t * 8192 + q * 512 + lane * 8;
        *(s16x8*)dh = hh;
        *(s16x8*)(dh + 4096) = ll;
    }
}

// ---------------------------------------------------------------------------
// Main: block = 128 rows (4 waves x 32 rows), iterate all 64 code-tiles from a
// double-buffered LDS copy of wfrag shared by all waves. 3-chain split-bf16
// MFMA, per-row top-2, margin flags, fused z_q gather.
// Score = w2 - 2*dot (x2 row-constant; rescue handles near-ties np-exactly).
// Fragment mappings verified rounds 7-11 (absmax=0).
// ---------------------------------------------------------------------------
__global__ __launch_bounds__(256, 1) void vq_mfma(
    const float* __restrict__ x, const uint4* __restrict__ wfrag4,
    const float* __restrict__ w2g, const float* __restrict__ w,
    float* __restrict__ zout, float* __restrict__ zq,
    int* __restrict__ flagcnt, int* __restrict__ flaglist) {
    __shared__ uint4 tiles[2][1024];   // 2 x 16KB: [0..511]=hi frags, [512..1023]=lo
    __shared__ float sw2[K_CODES];
    __shared__ int widx_s[128];

    const int tid = threadIdx.x;
    const int wave = tid >> 6;
    const int lane = tid & 63;
    const int rowblk = blockIdx.x * 128;
    const int rowbase = rowblk + wave * 32;

    for (int i = tid; i < K_CODES; i += 256) sw2[i] = w2g[i];

    // ---- A fragments: inline f32 -> bf16 hi/lo split, once per block ----
    s16x8 ahi0[8], alo0[8], ahi1[8], alo1[8];
    {
        const float* xr0 = x + (size_t)(rowbase + (lane & 15)) * DIM + (lane >> 4) * 8;
        const float* xr1 = xr0 + 16 * DIM;
#pragma unroll
        for (int q = 0; q < 8; ++q) {
            float4 a = *(const float4*)(xr0 + q * 32);
            float4 b = *(const float4*)(xr0 + q * 32 + 4);
            float e0[8] = {a.x, a.y, a.z, a.w, b.x, b.y, b.z, b.w};
            float4 c = *(const float4*)(xr1 + q * 32);
            float4 d = *(const float4*)(xr1 + q * 32 + 4);
            float e1[8] = {c.x, c.y, c.z, c.w, d.x, d.y, d.z, d.w};
#pragma unroll
            for (int i = 0; i < 8; ++i) {
                unsigned short h0 = bf16_rne(e0[i]);
                ahi0[q][i] = (short)h0;
                alo0[q][i] = (short)bf16_rne(e0[i] - bf16_f32(h0));
                unsigned short h1 = bf16_rne(e1[i]);
                ahi1[q][i] = (short)h1;
                alo1[q][i] = (short)bf16_rne(e1[i] - bf16_f32(h1));
            }
        }
    }

    // ---- prologue: stage tile 0 (each wave copies its 4KB chunk) ----
#pragma unroll
    for (int s = 0; s < 4; ++s) {
        int idx = wave * 256 + s * 64 + lane;
        tiles[0][idx] = wfrag4[idx];
    }

    float b1[2][4], b2[2][4];
    int i1[2][4];
#pragma unroll
    for (int rf = 0; rf < 2; ++rf)
#pragma unroll
        for (int j = 0; j < 4; ++j) { b1[rf][j] = INFINITY; b2[rf][j] = INFINITY; i1[rf][j] = 0; }

    __syncthreads();

    int cur = 0;
    for (int ct = 0; ct < 64; ++ct) {
        // prefetch next tile into regs (latency hidden under MFMAs)
        uint4 pf0, pf1, pf2, pf3;
        if (ct < 63) {
            const uint4* g = wfrag4 + (size_t)(ct + 1) * 1024 + wave * 256 + lane;
            pf0 = g[0]; pf1 = g[64]; pf2 = g[128]; pf3 = g[192];
        }
        // compute from tiles[cur]
        const uint4* th = tiles[cur];
        f32x4v a0hh = {0.f, 0.f, 0.f, 0.f};
        f32x4v a0hl = {0.f, 0.f, 0.f, 0.f};
        f32x4v a0lh = {0.f, 0.f, 0.f, 0.f};
        f32x4v a1hh = {0.f, 0.f, 0.f, 0.f};
        f32x4v a1hl = {0.f, 0.f, 0.f, 0.f};
        f32x4v a1lh = {0.f, 0.f, 0.f, 0.f};
#pragma unroll
        for (int q = 0; q < 8; ++q) {
            s16x8 Bh = *(const s16x8*)&th[q * 64 + lane];
            s16x8 Bl = *(const s16x8*)&th[512 + q * 64 + lane];
            a0hh = __builtin_amdgcn_mfma_f32_16x16x32_bf16(ahi0[q], Bh, a0hh, 0, 0, 0);
            a0hl = __builtin_amdgcn_mfma_f32_16x16x32_bf16(ahi0[q], Bl, a0hl, 0, 0, 0);
            a0lh = __builtin_amdgcn_mfma_f32_16x16x32_bf16(alo0[q], Bh, a0lh, 0, 0, 0);
            a1hh = __builtin_amdgcn_mfma_f32_16x16x32_bf16(ahi1[q], Bh, a1hh, 0, 0, 0);
            a1hl = __builtin_amdgcn_mfma_f32_16x16x32_bf16(ahi1[q], Bl, a1hl, 0, 0, 0);
            a1lh = __builtin_amdgcn_mfma_f32_16x16x32_bf16(alo1[q], Bh, a1lh, 0, 0, 0);
        }
        const int code = ct * 16 + (lane & 15);
        const float w2v = sw2[code];
#pragma unroll
        for (int j = 0; j < 4; ++j) {
            float d0 = (a0hh[j] + a0hl[j]) + a0lh[j];
            float s0 = w2v - 2.0f * d0;
            if (s0 < b2[0][j]) {
                if (s0 < b1[0][j]) { b2[0][j] = b1[0][j]; b1[0][j] = s0; i1[0][j] = code; }
                else b2[0][j] = s0;
            }
            float d1 = (a1hh[j] + a1hl[j]) + a1lh[j];
            float s1 = w2v - 2.0f * d1;
            if (s1 < b2[1][j]) {
                if (s1 < b1[1][j]) { b2[1][j] = b1[1][j]; b1[1][j] = s1; i1[1][j] = code; }
                else b2[1][j] = s1;
            }
        }
        // write prefetched tile to the other buffer
        if (ct < 63) {
            uint4* d = &tiles[cur ^ 1][wave * 256 + lane];
            d[0] = pf0; d[64] = pf1; d[128] = pf2; d[192] = pf3;
            cur ^= 1;
        }
        __syncthreads();
    }

    // butterfly top-2 reduce across the 16-lane col group (masks 1,2,4,8)
#pragma unroll
    for (int m = 1; m < 16; m <<= 1) {
#pragma unroll
        for (int rf = 0; rf < 2; ++rf)
#pragma unroll
            for (int j = 0; j < 4; ++j) {
                float ov1 = __shfl_xor(b1[rf][j], m);
                int oi = __shfl_xor(i1[rf][j], m);
                float ov2 = __shfl_xor(b2[rf][j], m);
                float nb2 = fminf(fmaxf(b1[rf][j], ov1), fminf(b2[rf][j], ov2));
                if (ov1 < b1[rf][j] || (ov1 == b1[rf][j] && oi < i1[rf][j])) {
                    b1[rf][j] = ov1; i1[rf][j] = oi;
                }
                b2[rf][j] = nb2;
            }
    }
    if ((lane & 15) == 0) {
#pragma unroll
        for (int rf = 0; rf < 2; ++rf)
#pragma unroll
            for (int j = 0; j < 4; ++j) {
                int rl = wave * 32 + rf * 16 + (lane >> 4) * 4 + j;
                int gi = i1[rf][j];
                widx_s[rl] = gi;
                zout[rowblk + rl] = (float)gi;
                if (b2[rf][j] - b1[rf][j] < MARGIN) {
                    int slot = atomicAdd(flagcnt, 1);
                    flaglist[slot] = rowblk + rl;
                }
            }
    }
    __syncthreads();

    // fused gather: 128 rows x 64 float4
    const float4* w4 = (const float4*)w;
    float4* zq4 = (float4*)zq;
#pragma unroll
    for (int p = 0; p < 32; ++p) {
        int lin = p * 256 + tid;
        int row = lin >> 6, qq = lin & 63;
        zq4[(size_t)(rowblk + row) * 64 + qq] = w4[(size_t)widx_s[row] * 64 + qq];
    }
}

// ---------------------------------------------------------------------------
// Exact np-f32 rescore of compacted flagged rows (round-5-verified semantics;
// k4-outer/cc-inner, no spill — round 10/11 lesson).
// ---------------------------------------------------------------------------
__global__ __launch_bounds__(256) void rescue_kernel(
    const float* __restrict__ x, const float* __restrict__ w,
    const float* __restrict__ w2g, const int* __restrict__ flagcnt,
    const int* __restrict__ flaglist, float* __restrict__ zout,
    float* __restrict__ zq) {
    __shared__ __align__(16) float xs[DIM];
    __shared__ float dv[256];
    __shared__ int di[256];
    __shared__ int mi_s;
    __shared__ float x2_s;
    const int tid = threadIdx.x;
    const int cnt = flagcnt[0];
    for (int f = blockIdx.x; f < cnt; f += gridDim.x) {
        const int r = flaglist[f];
        __syncthreads();
        for (int i = tid; i < DIM; i += 256) xs[i] = x[(size_t)r * DIM + i];
        __syncthreads();
        if (tid == 0)
            x2_s = np_block128_sumsq(xs) + np_block128_sumsq(xs + 128);
        __syncthreads();
        const float x2vv = x2_s;
        const float4* xs4 = (const float4*)xs;
        const float4* wr0 = (const float4*)(w + (size_t)(tid + 0 * 256) * DIM);
        const float4* wr1 = (const float4*)(w + (size_t)(tid + 1 * 256) * DIM);
        const float4* wr2 = (const float4*)(w + (size_t)(tid + 2 * 256) * DIM);
        const float4* wr3 = (const float4*)(w + (size_t)(tid + 3 * 256) * DIM);
        float acc0 = 0.f, acc1 = 0.f, acc2 = 0.f, acc3 = 0.f;
#pragma unroll 4
        for (int k4 = 0; k4 < DIM / 4; ++k4) {
            float4 xv = xs4[k4];
            float4 w0 = wr0[k4], w1 = wr1[k4], w2 = wr2[k4], w3 = wr3[k4];
            acc0 = __builtin_fmaf(xv.x, w0.x, acc0);
            acc0 = __builtin_fmaf(xv.y, w0.y, acc0);
            acc0 = __builtin_fmaf(xv.z, w0.z, acc0);
            acc0 = __builtin_fmaf(xv.w, w0.w, acc0);
            acc1 = __builtin_fmaf(xv.x, w1.x, acc1);
            acc1 = __builtin_fmaf(xv.y, w1.y, acc1);
            acc1 = __builtin_fmaf(xv.z, w1.z, acc1);
            acc1 = __builtin_fmaf(xv.w, w1.w, acc1);
            acc2 = __builtin_fmaf(xv.x, w2.x, acc2);
            acc2 = __builtin_fmaf(xv.y, w2.y, acc2);
            acc2 = __builtin_fmaf(xv.z, w2.z, acc2);
            acc2 = __builtin_fmaf(xv.w, w2.w, acc2);
            acc3 = __builtin_fmaf(xv.x, w3.x, acc3);
            acc3 = __builtin_fmaf(xv.y, w3.y, acc3);
            acc3 = __builtin_fmaf(xv.z, w3.z, acc3);
            acc3 = __builtin_fmaf(xv.w, w3.w, acc3);
        }
        float bv = INFINITY;
        int bi = 0;
        float accs[4] = {acc0, acc1, acc2, acc3};
#pragma unroll
        for (int cc = 0; cc < 4; ++cc) {
            int c = tid + cc * 256;
            float s = (x2vv - 2.0f * accs[cc]) + w2g[c];
            if (s < bv) { bv = s; bi = c; }
        }
        dv[tid] = bv;
        di[tid] = bi;
        __syncthreads();
        if (tid == 0) {
            float mv = dv[0];
            int mi = di[0];
            for (int t = 1; t < 256; ++t)
                if (dv[t] < mv || (dv[t] == mv && di[t] < mi)) { mv = dv[t]; mi = di[t]; }
            zout[r] = (float)mi;
            mi_s = mi;
        }
        __syncthreads();
        zq[(size_t)r * DIM + tid] = w[(size_t)mi_s * DIM + tid];
    }
}

// ===========================================================================
// Fallback (round-5 passing LDS kernel) if ws is too small. Needs only x2/w2.
// ===========================================================================
#define BM 64
#define BN 128
#define BK 64
#define LDX 68

__global__ __launch_bounds__(256) void vq_kernel_lds(
    const float* __restrict__ x, const float* __restrict__ w,
    const float* __restrict__ x2g, const float* __restrict__ w2g,
    float* __restrict__ zout, float* __restrict__ zq) {
    __shared__ float xs[BM * LDX];
    __shared__ float ws_[BN * LDX];
    __shared__ float sw2[K_CODES];
    __shared__ float sx2[BM];
    __shared__ int widx[BM];

    const int tid = threadIdx.x;
    const int bm0 = blockIdx.x * BM;
    const int rg = tid & 15;
    const int cg = tid >> 4;

    for (int i = tid; i < K_CODES; i += 256) sw2[i] = w2g[i];
    if (tid < BM) sx2[tid] = x2g[bm0 + tid];

    float best[4];
    int bidx[4];
#pragma unroll
    for (int i = 0; i < 4; ++i) { best[i] = INFINITY; bidx[i] = 0; }

    const float4* x4 = (const float4*)x;
    const float4* w4 = (const float4*)w;

    for (int cn = 0; cn < K_CODES / BN; ++cn) {
        float acc[4][8];
#pragma unroll
        for (int i = 0; i < 4; ++i)
#pragma unroll
            for (int j = 0; j < 8; ++j) acc[i][j] = 0.f;

        for (int dk = 0; dk < DIM / BK; ++dk) {
            __syncthreads();
#pragma unroll
            for (int p = 0; p < 4; ++p) {
                int l = p * 256 + tid;
                int row = l >> 4, c4 = l & 15;
                float4 v = x4[(size_t)(bm0 + row) * (DIM / 4) + dk * (BK / 4) + c4];
                *(float4*)&xs[row * LDX + c4 * 4] = v;
            }
#pragma unroll
            for (int p = 0; p < 8; ++p) {
                int l = p * 256 + tid;
                int row = l >> 4, c4 = l & 15;
                float4 v = w4[(size_t)(cn * BN + row) * (DIM / 4) + dk * (BK / 4) + c4];
                *(float4*)&ws_[row * LDX + c4 * 4] = v;
            }
            __syncthreads();
#pragma unroll
            for (int d = 0; d < BK; d += 4) {
                float4 xv[4], wv[8];
#pragma unroll
                for (int i = 0; i < 4; ++i)
                    xv[i] = *(const float4*)&xs[(rg + 16 * i) * LDX + d];
#pragma unroll
                for (int j = 0; j < 8; ++j)
                    wv[j] = *(const float4*)&ws_[(cg + 16 * j) * LDX + d];
#pragma unroll
                for (int i = 0; i < 4; ++i)
#pragma unroll
                    for (int j = 0; j < 8; ++j) {
                        acc[i][j] = __builtin_fmaf(xv[i].x, wv[j].x, acc[i][j]);
                        acc[i][j] = __builtin_fmaf(xv[i].y, wv[j].y, acc[i][j]);
                        acc[i][j] = __builtin_fmaf(xv[i].z, wv[j].z, acc[i][j]);
                        acc[i][j] = __builtin_fmaf(xv[i].w, wv[j].w, acc[i][j]);
                    }
            }
        }
#pragma unroll
        for (int j = 0; j < 8; ++j) {
            int c = cn * BN + cg + 16 * j;
            float w2v = sw2[c];
#pragma unroll
            for (int i = 0; i < 4; ++i) {
                float t = sx2[rg + 16 * i] - 2.0f * acc[i][j];
                float s = t + w2v;
                if (s < best[i]) { best[i] = s; bidx[i] = c; }
            }
        }
    }

    __syncthreads();
    float* sval = xs;
    int* sidx = (int*)(xs + 64 * 17);
#pragma unroll
    for (int i = 0; i < 4; ++i) {
        sval[(rg + 16 * i) * 17 + cg] = best[i];
        sidx[(rg + 16 * i) * 17 + cg] = bidx[i];
    }
    __syncthreads();
    if (tid < BM) {
        float bv = INFINITY;
        int bi = 0;
        for (int c = 0; c < 16; ++c) {
            float v = sval[tid * 17 + c];
            int id = sidx[tid * 17 + c];
            if (v < bv || (v == bv && id < bi)) { bv = v; bi = id; }
        }
        widx[tid] = bi;
        zout[bm0 + tid] = (float)bi;
    }
    __syncthreads();
    float4* zq4 = (float4*)zq;
#pragma unroll
    for (int p = 0; p < 16; ++p) {
        int lin = p * 256 + tid;
        int row = lin >> 6, q = lin & 63;
        zq4[(size_t)(bm0 + row) * 64 + q] = w4[(size_t)widx[row] * 64 + q];
    }
}

extern "C" void kernel_launch(void* const* d_in, const int* in_sizes, int n_in,
                              void* d_out, int out_size, void* d_ws, size_t ws_size,
                              hipStream_t stream) {
    const float* z_e = (const float*)d_in[0];
    const float* emb = (const float*)d_in[1];
    float* x2g = (float*)d_ws;                                   // fallback x2
    int* flaglist = (int*)d_ws;                                  // MFMA path [32768]
    float* w2g = x2g + N_ROWS;                                   // [1024]
    unsigned short* wfrag = (unsigned short*)(w2g + K_CODES);    // [524288] = 1 MB
    int* flagcnt = (int*)(wfrag + (size_t)2 * K_CODES * DIM);    // [1]
    float* zout = (float*)d_out;                                 // [32768]
    float* zq = (float*)d_out + N_ROWS;                          // [32768*256]

    if (ws_size >= WS_NEEDED) {
        zero_kernel<<<1, 64, 0, stream>>>(flagcnt);
        wprep_kernel<<<K_CODES / 16, 64, 0, stream>>>(emb, w2g, wfrag);
        vq_mfma<<<N_ROWS / 128, 256, 0, stream>>>(z_e, (const uint4*)wfrag, w2g,
                                                  emb, zout, zq, flagcnt, flaglist);
        rescue_kernel<<<256, 256, 0, stream>>>(z_e, emb, w2g, flagcnt,
                                               flaglist, zout, zq);
    } else {
        npsumsq_kernel<<<N_ROWS / 16, 64, 0, stream>>>(z_e, x2g);
        npsumsq_kernel<<<K_CODES / 16, 64, 0, stream>>>(emb, w2g);
        vq_kernel_lds<<<N_ROWS / BM, 256, 0, stream>>>(z_e, emb, x2g, w2g, zout, zq);
    }
}

// Round 15
// 136.129 us; speedup vs baseline: 2.3826x; 1.1063x over previous
//
#include <hip/hip_runtime.h>
#include <math.h>

#define N_ROWS 32768
#define DIM 256
#define K_CODES 1024
#define MARGIN 2e-3f

typedef float f32x4v __attribute__((ext_vector_type(4)));
typedef short s16x8 __attribute__((ext_vector_type(8)));

// ---- ws layout (bytes) ----
// flaglist int[32768]       @ 0        (fallback uses as x2 floats)
// w2       float[1024]      @ 131072
// wfrag    ushort[524288]   @ 135168   (64 tiles x 16KB, fragment-major)
// flagcnt  int              @ 1183744
#define WS_NEEDED ((size_t)1183748)

__device__ __forceinline__ unsigned short bf16_rne(float f) {
    unsigned int u = __float_as_uint(f);
    unsigned int r = (u + 0x7FFFu + ((u >> 16) & 1u)) >> 16;
    return (unsigned short)r;
}
__device__ __forceinline__ float bf16_f32(unsigned short h) {
    return __uint_as_float(((unsigned int)h) << 16);
}

// ---------------------------------------------------------------------------
// numpy-replica pairwise sum of squares (AVX512 path) — bitwise == np.sum(x*x)
// ---------------------------------------------------------------------------
__device__ __forceinline__ float np_block128_sumsq(const float* e) {
#pragma clang fp contract(off)
    float s[16];
#pragma unroll
    for (int l = 0; l < 16; ++l) {
        float a0 = e[l]       * e[l];
        float a1 = e[16 + l]  * e[16 + l];
        float a2 = e[32 + l]  * e[32 + l];
        float a3 = e[48 + l]  * e[48 + l];
        float a4 = e[64 + l]  * e[64 + l];
        float a5 = e[80 + l]  * e[80 + l];
        float a6 = e[96 + l]  * e[96 + l];
        float a7 = e[112 + l] * e[112 + l];
        s[l] = ((a0 + a1) + (a2 + a3)) + ((a4 + a5) + (a6 + a7));
    }
    float t1[8];
#pragma unroll
    for (int i = 0; i < 8; ++i) t1[i] = s[i] + s[i + 8];
    float t2[4];
#pragma unroll
    for (int i = 0; i < 4; ++i) t2[i] = t1[i] + t1[i + 4];
    return (t2[0] + t2[2]) + (t2[1] + t2[3]);
}

__global__ __launch_bounds__(64) void npsumsq_kernel(const float* __restrict__ src,
                                                     float* __restrict__ dst) {
    __shared__ float buf[16][257];
    const int tid = threadIdx.x;
    const int r0 = blockIdx.x * 16;
#pragma unroll
    for (int it = 0; it < 16; ++it) {
        int idx = it * 64 + tid;
        int r = idx >> 6, c4 = idx & 63;
        float4 v = ((const float4*)(src + (size_t)(r0 + r) * DIM))[c4];
        buf[r][c4 * 4 + 0] = v.x;
        buf[r][c4 * 4 + 1] = v.y;
        buf[r][c4 * 4 + 2] = v.z;
        buf[r][c4 * 4 + 3] = v.w;
    }
    __syncthreads();
    if (tid < 16) {
        const float* e = buf[tid];
        dst[r0 + tid] = np_block128_sumsq(e) + np_block128_sumsq(e + 128);
    }
}

__global__ void zero_kernel(int* p) { if (threadIdx.x == 0) p[0] = 0; }

// ---------------------------------------------------------------------------
// wprep: per 16-code tile, w2 (np tree) + bf16 hi/lo splits in FRAGMENT-MAJOR
// layout: tile t = 16384 B; hi frag bytes q*1024 + lane*16 hold
// w[t*16 + (lane&15)][q*32 + (lane>>4)*8 + i]; lo at +8192 B.
// ---------------------------------------------------------------------------
__global__ __launch_bounds__(64) void wprep_kernel(const float* __restrict__ w,
                                                   float* __restrict__ w2,
                                                   unsigned short* __restrict__ wfrag) {
    __shared__ float buf[16][257];
    const int lane = threadIdx.x;
    const int t = blockIdx.x;
    const int r0 = t * 16;
#pragma unroll
    for (int it = 0; it < 16; ++it) {
        int idx = it * 64 + lane;
        int r = idx >> 6, c4 = idx & 63;
        float4 v = ((const float4*)(w + (size_t)(r0 + r) * DIM))[c4];
        buf[r][c4 * 4 + 0] = v.x;
        buf[r][c4 * 4 + 1] = v.y;
        buf[r][c4 * 4 + 2] = v.z;
        buf[r][c4 * 4 + 3] = v.w;
    }
    __syncthreads();
    if (lane < 16) {
        const float* e = buf[lane];
        w2[r0 + lane] = np_block128_sumsq(e) + np_block128_sumsq(e + 128);
    }
    const int c = lane & 15, ko = lane >> 4;
#pragma unroll
    for (int q = 0; q < 8; ++q) {
        s16x8 hh, ll;
#pragma unroll
        for (int i = 0; i < 8; ++i) {
            float f = buf[c][q * 32 + ko * 8 + i];
            unsigned short h = bf16_rne(f);
            hh[i] = (short)h;
            ll[i] = (short)bf16_rne(f - bf16_f32(h));
        }
        unsigned short* dh = wfrag + (size_t)t * 8192 + q * 512 + lane * 8;
        *(s16x8*)dh = hh;
        *(s16x8*)(dh + 4096) = ll;
    }
}

// ---------------------------------------------------------------------------
// Main: block = 128 rows, 8 waves x 16 rows (512 thr) -> 2 waves/SIMD so MFMA
// of one wave overlaps VALU/LDS of another (m114). All waves share the
// double-buffered LDS code tile; each wave owns its rows -> no cross-wave
// merge. 3-chain split-bf16 MFMA; score = w2 - 2*dot; margin flags; fused
// gather. Fragment mappings verified rounds 7-12 (absmax=0).
// ---------------------------------------------------------------------------
__global__ __launch_bounds__(512, 1) void vq_mfma(
    const float* __restrict__ x, const uint4* __restrict__ wfrag4,
    const float* __restrict__ w2g, const float* __restrict__ w,
    float* __restrict__ zout, float* __restrict__ zq,
    int* __restrict__ flagcnt, int* __restrict__ flaglist) {
    __shared__ uint4 tiles[2][1024];   // 2 x 16KB: [0..511]=hi frags, [512..1023]=lo
    __shared__ float sw2[K_CODES];
    __shared__ int widx_s[128];

    const int tid = threadIdx.x;
    const int wave = tid >> 6;        // 0..7
    const int lane = tid & 63;
    const int rowblk = blockIdx.x * 128;
    const int rowbase = rowblk + wave * 16;

    for (int i = tid; i < K_CODES; i += 512) sw2[i] = w2g[i];

    // ---- A fragments: inline f32 -> bf16 hi/lo split (16 rows per wave) ----
    s16x8 ahi[8], alo[8];
    {
        const float* xr = x + (size_t)(rowbase + (lane & 15)) * DIM + (lane >> 4) * 8;
#pragma unroll
        for (int q = 0; q < 8; ++q) {
            float4 a = *(const float4*)(xr + q * 32);
            float4 b = *(const float4*)(xr + q * 32 + 4);
            float e[8] = {a.x, a.y, a.z, a.w, b.x, b.y, b.z, b.w};
#pragma unroll
            for (int i = 0; i < 8; ++i) {
                unsigned short h = bf16_rne(e[i]);
                ahi[q][i] = (short)h;
                alo[q][i] = (short)bf16_rne(e[i] - bf16_f32(h));
            }
        }
    }

    // ---- prologue: stage tile 0 (1024 uint4 / 512 threads) ----
    tiles[0][tid] = wfrag4[tid];
    tiles[0][tid + 512] = wfrag4[tid + 512];

    float b1[4], b2[4];
    int i1[4];
#pragma unroll
    for (int j = 0; j < 4; ++j) { b1[j] = INFINITY; b2[j] = INFINITY; i1[j] = 0; }

    __syncthreads();

    int cur = 0;
    for (int ct = 0; ct < 64; ++ct) {
        // prefetch next tile into regs (hidden under MFMAs)
        uint4 pf0, pf1;
        if (ct < 63) {
            const uint4* g = wfrag4 + (size_t)(ct + 1) * 1024;
            pf0 = g[tid];
            pf1 = g[tid + 512];
        }
        const uint4* th = tiles[cur];
        f32x4v ahh = {0.f, 0.f, 0.f, 0.f};
        f32x4v ahl = {0.f, 0.f, 0.f, 0.f};
        f32x4v alh = {0.f, 0.f, 0.f, 0.f};
#pragma unroll
        for (int q = 0; q < 8; ++q) {
            s16x8 Bh = *(const s16x8*)&th[q * 64 + lane];
            s16x8 Bl = *(const s16x8*)&th[512 + q * 64 + lane];
            ahh = __builtin_amdgcn_mfma_f32_16x16x32_bf16(ahi[q], Bh, ahh, 0, 0, 0);
            ahl = __builtin_amdgcn_mfma_f32_16x16x32_bf16(ahi[q], Bl, ahl, 0, 0, 0);
            alh = __builtin_amdgcn_mfma_f32_16x16x32_bf16(alo[q], Bh, alh, 0, 0, 0);
        }
        const int code = ct * 16 + (lane & 15);
        const float w2v = sw2[code];
#pragma unroll
        for (int j = 0; j < 4; ++j) {
            float d = (ahh[j] + ahl[j]) + alh[j];
            float s = w2v - 2.0f * d;
            if (s < b2[j]) {
                if (s < b1[j]) { b2[j] = b1[j]; b1[j] = s; i1[j] = code; }
                else b2[j] = s;
            }
        }
        if (ct < 63) {
            uint4* d = tiles[cur ^ 1];
            d[tid] = pf0;
            d[tid + 512] = pf1;
            cur ^= 1;
        }
        __syncthreads();
    }

    // butterfly top-2 reduce across the 16-lane code group (masks 1,2,4,8)
#pragma unroll
    for (int m = 1; m < 16; m <<= 1) {
#pragma unroll
        for (int j = 0; j < 4; ++j) {
            float ov1 = __shfl_xor(b1[j], m);
            int oi = __shfl_xor(i1[j], m);
            float ov2 = __shfl_xor(b2[j], m);
            float nb2 = fminf(fmaxf(b1[j], ov1), fminf(b2[j], ov2));
            if (ov1 < b1[j] || (ov1 == b1[j] && oi < i1[j])) { b1[j] = ov1; i1[j] = oi; }
            b2[j] = nb2;
        }
    }
    if ((lane & 15) == 0) {
#pragma unroll
        for (int j = 0; j < 4; ++j) {
            int rl = wave * 16 + (lane >> 4) * 4 + j;
            widx_s[rl] = i1[j];
            zout[rowblk + rl] = (float)i1[j];
            if (b2[j] - b1[j] < MARGIN) {
                int slot = atomicAdd(flagcnt, 1);
                flaglist[slot] = rowblk + rl;
            }
        }
    }
    __syncthreads();

    // fused gather: 128 rows x 64 float4 = 8192 / 512 threads
    const float4* w4 = (const float4*)w;
    float4* zq4 = (float4*)zq;
#pragma unroll
    for (int p = 0; p < 16; ++p) {
        int lin = p * 512 + tid;
        int row = lin >> 6, qq = lin & 63;
        zq4[(size_t)(rowblk + row) * 64 + qq] = w4[(size_t)widx_s[row] * 64 + qq];
    }
}

// ---------------------------------------------------------------------------
// Exact np-f32 rescore of compacted flagged rows (round-5-verified semantics;
// k4-outer/cc-inner, no spill — round 10/11 lesson).
// ---------------------------------------------------------------------------
__global__ __launch_bounds__(256) void rescue_kernel(
    const float* __restrict__ x, const float* __restrict__ w,
    const float* __restrict__ w2g, const int* __restrict__ flagcnt,
    const int* __restrict__ flaglist, float* __restrict__ zout,
    float* __restrict__ zq) {
    __shared__ __align__(16) float xs[DIM];
    __shared__ float dv[256];
    __shared__ int di[256];
    __shared__ int mi_s;
    __shared__ float x2_s;
    const int tid = threadIdx.x;
    const int cnt = flagcnt[0];
    for (int f = blockIdx.x; f < cnt; f += gridDim.x) {
        const int r = flaglist[f];
        __syncthreads();
        for (int i = tid; i < DIM; i += 256) xs[i] = x[(size_t)r * DIM + i];
        __syncthreads();
        if (tid == 0)
            x2_s = np_block128_sumsq(xs) + np_block128_sumsq(xs + 128);
        __syncthreads();
        const float x2vv = x2_s;
        const float4* xs4 = (const float4*)xs;
        const float4* wr0 = (const float4*)(w + (size_t)(tid + 0 * 256) * DIM);
        const float4* wr1 = (const float4*)(w + (size_t)(tid + 1 * 256) * DIM);
        const float4* wr2 = (const float4*)(w + (size_t)(tid + 2 * 256) * DIM);
        const float4* wr3 = (const float4*)(w + (size_t)(tid + 3 * 256) * DIM);
        float acc0 = 0.f, acc1 = 0.f, acc2 = 0.f, acc3 = 0.f;
#pragma unroll 4
        for (int k4 = 0; k4 < DIM / 4; ++k4) {
            float4 xv = xs4[k4];
            float4 w0 = wr0[k4], w1 = wr1[k4], w2 = wr2[k4], w3 = wr3[k4];
            acc0 = __builtin_fmaf(xv.x, w0.x, acc0);
            acc0 = __builtin_fmaf(xv.y, w0.y, acc0);
            acc0 = __builtin_fmaf(xv.z, w0.z, acc0);
            acc0 = __builtin_fmaf(xv.w, w0.w, acc0);
            acc1 = __builtin_fmaf(xv.x, w1.x, acc1);
            acc1 = __builtin_fmaf(xv.y, w1.y, acc1);
            acc1 = __builtin_fmaf(xv.z, w1.z, acc1);
            acc1 = __builtin_fmaf(xv.w, w1.w, acc1);
            acc2 = __builtin_fmaf(xv.x, w2.x, acc2);
            acc2 = __builtin_fmaf(xv.y, w2.y, acc2);
            acc2 = __builtin_fmaf(xv.z, w2.z, acc2);
            acc2 = __builtin_fmaf(xv.w, w2.w, acc2);
            acc3 = __builtin_fmaf(xv.x, w3.x, acc3);
            acc3 = __builtin_fmaf(xv.y, w3.y, acc3);
            acc3 = __builtin_fmaf(xv.z, w3.z, acc3);
            acc3 = __builtin_fmaf(xv.w, w3.w, acc3);
        }
        float bv = INFINITY;
        int bi = 0;
        float accs[4] = {acc0, acc1, acc2, acc3};
#pragma unroll
        for (int cc = 0; cc < 4; ++cc) {
            int c = tid + cc * 256;
            float s = (x2vv - 2.0f * accs[cc]) + w2g[c];
            if (s < bv) { bv = s; bi = c; }
        }
        dv[tid] = bv;
        di[tid] = bi;
        __syncthreads();
        if (tid == 0) {
            float mv = dv[0];
            int mi = di[0];
            for (int t = 1; t < 256; ++t)
                if (dv[t] < mv || (dv[t] == mv && di[t] < mi)) { mv = dv[t]; mi = di[t]; }
            zout[r] = (float)mi;
            mi_s = mi;
        }
        __syncthreads();
        zq[(size_t)r * DIM + tid] = w[(size_t)mi_s * DIM + tid];
    }
}

// ===========================================================================
// Fallback (round-5 passing LDS kernel) if ws is too small. Needs only x2/w2.
// ===========================================================================
#define BM 64
#define BN 128
#define BK 64
#define LDX 68

__global__ __launch_bounds__(256) void vq_kernel_lds(
    const float* __restrict__ x, const float* __restrict__ w,
    const float* __restrict__ x2g, const float* __restrict__ w2g,
    float* __restrict__ zout, float* __restrict__ zq) {
    __shared__ float xs[BM * LDX];
    __shared__ float ws_[BN * LDX];
    __shared__ float sw2[K_CODES];
    __shared__ float sx2[BM];
    __shared__ int widx[BM];

    const int tid = threadIdx.x;
    const int bm0 = blockIdx.x * BM;
    const int rg = tid & 15;
    const int cg = tid >> 4;

    for (int i = tid; i < K_CODES; i += 256) sw2[i] = w2g[i];
    if (tid < BM) sx2[tid] = x2g[bm0 + tid];

    float best[4];
    int bidx[4];
#pragma unroll
    for (int i = 0; i < 4; ++i) { best[i] = INFINITY; bidx[i] = 0; }

    const float4* x4 = (const float4*)x;
    const float4* w4 = (const float4*)w;

    for (int cn = 0; cn < K_CODES / BN; ++cn) {
        float acc[4][8];
#pragma unroll
        for (int i = 0; i < 4; ++i)
#pragma unroll
            for (int j = 0; j < 8; ++j) acc[i][j] = 0.f;

        for (int dk = 0; dk < DIM / BK; ++dk) {
            __syncthreads();
#pragma unroll
            for (int p = 0; p < 4; ++p) {
                int l = p * 256 + tid;
                int row = l >> 4, c4 = l & 15;
                float4 v = x4[(size_t)(bm0 + row) * (DIM / 4) + dk * (BK / 4) + c4];
                *(float4*)&xs[row * LDX + c4 * 4] = v;
            }
#pragma unroll
            for (int p = 0; p < 8; ++p) {
                int l = p * 256 + tid;
                int row = l >> 4, c4 = l & 15;
                float4 v = w4[(size_t)(cn * BN + row) * (DIM / 4) + dk * (BK / 4) + c4];
                *(float4*)&ws_[row * LDX + c4 * 4] = v;
            }
            __syncthreads();
#pragma unroll
            for (int d = 0; d < BK; d += 4) {
                float4 xv[4], wv[8];
#pragma unroll
                for (int i = 0; i < 4; ++i)
                    xv[i] = *(const float4*)&xs[(rg + 16 * i) * LDX + d];
#pragma unroll
                for (int j = 0; j < 8; ++j)
                    wv[j] = *(const float4*)&ws_[(cg + 16 * j) * LDX + d];
#pragma unroll
                for (int i = 0; i < 4; ++i)
#pragma unroll
                    for (int j = 0; j < 8; ++j) {
                        acc[i][j] = __builtin_fmaf(xv[i].x, wv[j].x, acc[i][j]);
                        acc[i][j] = __builtin_fmaf(xv[i].y, wv[j].y, acc[i][j]);
                        acc[i][j] = __builtin_fmaf(xv[i].z, wv[j].z, acc[i][j]);
                        acc[i][j] = __builtin_fmaf(xv[i].w, wv[j].w, acc[i][j]);
                    }
            }
        }
#pragma unroll
        for (int j = 0; j < 8; ++j) {
            int c = cn * BN + cg + 16 * j;
            float w2v = sw2[c];
#pragma unroll
            for (int i = 0; i < 4; ++i) {
                float t = sx2[rg + 16 * i] - 2.0f * acc[i][j];
                float s = t + w2v;
                if (s < best[i]) { best[i] = s; bidx[i] = c; }
            }
        }
    }

    __syncthreads();
    float* sval = xs;
    int* sidx = (int*)(xs + 64 * 17);
#pragma unroll
    for (int i = 0; i < 4; ++i) {
        sval[(rg + 16 * i) * 17 + cg] = best[i];
        sidx[(rg + 16 * i) * 17 + cg] = bidx[i];
    }
    __syncthreads();
    if (tid < BM) {
        float bv = INFINITY;
        int bi = 0;
        for (int c = 0; c < 16; ++c) {
            float v = sval[tid * 17 + c];
            int id = sidx[tid * 17 + c];
            if (v < bv || (v == bv && id < bi)) { bv = v; bi = id; }
        }
        widx[tid] = bi;
        zout[bm0 + tid] = (float)bi;
    }
    __syncthreads();
    float4* zq4 = (float4*)zq;
#pragma unroll
    for (int p = 0; p < 16; ++p) {
        int lin = p * 256 + tid;
        int row = lin >> 6, q = lin & 63;
        zq4[(size_t)(bm0 + row) * 64 + q] = w4[(size_t)widx[row] * 64 + q];
    }
}

extern "C" void kernel_launch(void* const* d_in, const int* in_sizes, int n_in,
                              void* d_out, int out_size, void* d_ws, size_t ws_size,
                              hipStream_t stream) {
    const float* z_e = (const float*)d_in[0];
    const float* emb = (const float*)d_in[1];
    float* x2g = (float*)d_ws;                                   // fallback x2
    int* flaglist = (int*)d_ws;                                  // MFMA path [32768]
    float* w2g = x2g + N_ROWS;                                   // [1024]
    unsigned short* wfrag = (unsigned short*)(w2g + K_CODES);    // [524288] = 1 MB
    int* flagcnt = (int*)(wfrag + (size_t)2 * K_CODES * DIM);    // [1]
    float* zout = (float*)d_out;                                 // [32768]
    float* zq = (float*)d_out + N_ROWS;                          // [32768*256]

    if (ws_size >= WS_NEEDED) {
        zero_kernel<<<1, 64, 0, stream>>>(flagcnt);
        wprep_kernel<<<K_CODES / 16, 64, 0, stream>>>(emb, w2g, wfrag);
        vq_mfma<<<N_ROWS / 128, 512, 0, stream>>>(z_e, (const uint4*)wfrag, w2g,
                                                  emb, zout, zq, flagcnt, flaglist);
        rescue_kernel<<<256, 256, 0, stream>>>(z_e, emb, w2g, flagcnt,
                                               flaglist, zout, zq);
    } else {
        npsumsq_kernel<<<N_ROWS / 16, 64, 0, stream>>>(z_e, x2g);
        npsumsq_kernel<<<K_CODES / 16, 64, 0, stream>>>(emb, w2g);
        vq_kernel_lds<<<N_ROWS / BM, 256, 0, stream>>>(z_e, emb, x2g, w2g, zout, zq);
    }
}